// Round 7
// baseline (455.739 us; speedup 1.0000x reference)
//
#include <hip/hip_runtime.h>
#include <hip/hip_bf16.h>
#include <math.h>

// Problem constants
constexpr int cB = 4, cT = 256, cS = 400, cD = 512, cV = 50000, cNX = 50;
constexpr int cVEXT = cV + cNX;           // 50050
constexpr int cPAN  = (cV + 127) / 128;   // 391 col panels of the big GEMM
constexpr int cCBLD = cVEXT * 2;          // ushort stride of one fp32 out row
constexpr int cMQ   = cB * cT;            // 1024

typedef __attribute__((ext_vector_type(8))) short short8v;   // 8 bf16
typedef __attribute__((ext_vector_type(4))) float floatx4;

__device__ inline ushort f2bf(float f) {
    union { float f; unsigned u; } v; v.f = f;
    unsigned r = (v.u + 0x7FFFu + ((v.u >> 16) & 1u)) >> 16;
    return (ushort)r;
}
__device__ inline float bf2f(ushort u) {
    union { unsigned u; float f; } v; v.u = ((unsigned)u) << 16;
    return v.f;
}

// ---------------------------------------------------------------------------
// fp32 -> bf16 cast
// ---------------------------------------------------------------------------
__global__ __launch_bounds__(256) void cast_kernel(
    const float* __restrict__ src, ushort* __restrict__ dst, int n4)
{
    const int stride = gridDim.x * 256;
    for (int i = blockIdx.x * 256 + threadIdx.x; i < n4; i += stride) {
        float4 v = *(const float4*)(src + (size_t)i * 4);
        ushort4 o;
        o.x = f2bf(v.x); o.y = f2bf(v.y); o.z = f2bf(v.z); o.w = f2bf(v.w);
        *(ushort4*)(dst + (size_t)i * 4) = o;
    }
}

// ---------------------------------------------------------------------------
// bf16 MFMA GEMM, 128x128 tile, BK=32, 4 waves (2x2), A+B double-buffered.
// STATS=true (big logits GEMM): XCD-chunked job swizzle over (panel,rowblock);
//   writes bf16 C (row stride cbld ushorts) + per-(panel,row) softmax partials
//   pm/ps in TRANSPOSED layout pm[pan*M + row] (contiguous per block).
// STATS=false: fp32 C with bias, stride ldc, plain blockIdx mapping.
// ---------------------------------------------------------------------------
template<bool STATS>
__global__ __launch_bounds__(256) void gemm2(
    const ushort* __restrict__ A, const ushort* __restrict__ Wb,
    const float* __restrict__ bias,
    float* __restrict__ Cf, ushort* __restrict__ Cb, int cbld,
    float* __restrict__ pm, float* __restrict__ ps,
    int M, int N, int K, int ldc)
{
    __shared__ ushort As[2][128 * 32];
    __shared__ ushort Bs[2][128 * 32];
    __shared__ float sm_m[2][128];
    __shared__ float sm_s[2][128];

    const int tid  = threadIdx.x;
    const int lane = tid & 63;
    const int wv   = tid >> 6;
    const int wm   = wv >> 1;
    const int wn   = wv & 1;

    int bm, bn, pan = 0;
    if constexpr (STATS) {
        // XCD-chunked swizzle: nwg = gridDim.x*gridDim.y, 8 | nwg
        const int wg  = blockIdx.y * gridDim.x + blockIdx.x;
        const int nwg = gridDim.x * gridDim.y;
        const int j   = (wg & 7) * (nwg >> 3) + (wg >> 3);
        pan = j >> 3;                  // gridDim.x == 8 row-blocks
        bm  = (j & 7) * 128;
        bn  = pan * 128;
    } else {
        bm = blockIdx.x * 128;
        bn = blockIdx.y * 128;
    }

    const int srow = lane >> 2;        // 0..15
    const int sk   = (lane & 3) * 8;   // bf16 elems

    const int nt = K >> 5;

    floatx4 acc[4][4] = {};

    auto stage = [&](int bidx, int t) {
        const int k0 = t * 32;
        #pragma unroll
        for (int c = 0; c < 2; ++c) {
            const int lr = wv * 32 + c * 16;
            int ga = bm + lr + srow; if (ga >= M) ga = M - 1;
            __builtin_amdgcn_global_load_lds(
                (const __attribute__((address_space(1))) void*)(A + (size_t)ga * K + k0 + sk),
                (__attribute__((address_space(3))) void*)&As[bidx][lr * 32], 16, 0, 0);
        }
        #pragma unroll
        for (int c = 0; c < 2; ++c) {
            const int lr = wv * 32 + c * 16;
            int gb = bn + lr + srow; if (gb >= N) gb = N - 1;
            __builtin_amdgcn_global_load_lds(
                (const __attribute__((address_space(1))) void*)(Wb + (size_t)gb * K + k0 + sk),
                (__attribute__((address_space(3))) void*)&Bs[bidx][lr * 32], 16, 0, 0);
        }
    };

    stage(0, 0);
    __syncthreads();

    const int fr = lane & 15;
    const int g  = lane >> 4;
    int buf = 0;

    for (int t = 0; t < nt; ++t) {
        if (t + 1 < nt) stage(buf ^ 1, t + 1);
        short8v a[4], b[4];
        #pragma unroll
        for (int mi = 0; mi < 4; ++mi)
            a[mi] = *(const short8v*)&As[buf][(wm * 64 + mi * 16 + fr) * 32 + g * 8];
        #pragma unroll
        for (int ni = 0; ni < 4; ++ni)
            b[ni] = *(const short8v*)&Bs[buf][(wn * 64 + ni * 16 + fr) * 32 + g * 8];
        #pragma unroll
        for (int mi = 0; mi < 4; ++mi)
            #pragma unroll
            for (int ni = 0; ni < 4; ++ni)
                acc[mi][ni] = __builtin_amdgcn_mfma_f32_16x16x32_bf16(
                    a[mi], b[ni], acc[mi][ni], 0, 0, 0);
        __syncthreads();
        buf ^= 1;
    }

    // ---- epilogue ----
    float bv[4]; bool val[4];
    #pragma unroll
    for (int ni = 0; ni < 4; ++ni) {
        const int colg = bn + wn * 64 + ni * 16 + fr;
        val[ni] = (colg < N);
        bv[ni] = val[ni] ? bias[colg] : 0.f;
    }
    #pragma unroll
    for (int mi = 0; mi < 4; ++mi)
        #pragma unroll
        for (int ni = 0; ni < 4; ++ni)
            #pragma unroll
            for (int r = 0; r < 4; ++r)
                acc[mi][ni][r] += bv[ni];

    if constexpr (STATS) {
        // per-(mi,r) row stats over this wave's 64 cols
        #pragma unroll
        for (int mi = 0; mi < 4; ++mi) {
            #pragma unroll
            for (int r = 0; r < 4; ++r) {
                float mx = -1e30f;
                #pragma unroll
                for (int ni = 0; ni < 4; ++ni)
                    if (val[ni]) mx = fmaxf(mx, acc[mi][ni][r]);
                #pragma unroll
                for (int sw = 1; sw < 16; sw <<= 1)
                    mx = fmaxf(mx, __shfl_xor(mx, sw));
                float sm = 0.f;
                #pragma unroll
                for (int ni = 0; ni < 4; ++ni)
                    if (val[ni]) sm += __expf(acc[mi][ni][r] - mx);
                #pragma unroll
                for (int sw = 1; sw < 16; sw <<= 1)
                    sm += __shfl_xor(sm, sw);
                if (fr == 0) {
                    const int rl = wm * 64 + mi * 16 + g * 4 + r;
                    sm_m[wn][rl] = mx;
                    sm_s[wn][rl] = sm;
                }
            }
        }
        __syncthreads();
        if (tid < 128) {
            const float m0 = sm_m[0][tid], m1 = sm_m[1][tid];
            const float s0 = sm_s[0][tid], s1 = sm_s[1][tid];
            const float mm = fmaxf(m0, m1);
            const float ss = s0 * __expf(m0 - mm) + s1 * __expf(m1 - mm);
            const int grow = bm + tid;
            if (grow < M) {
                pm[(size_t)pan * M + grow] = mm;   // transposed: contiguous
                ps[(size_t)pan * M + grow] = ss;
            }
        }
        // bf16 logits
        #pragma unroll
        for (int mi = 0; mi < 4; ++mi) {
            #pragma unroll
            for (int ni = 0; ni < 4; ++ni) {
                if (!val[ni]) continue;
                const int colg = bn + wn * 64 + ni * 16 + fr;
                #pragma unroll
                for (int r = 0; r < 4; ++r) {
                    const int row = bm + wm * 64 + mi * 16 + g * 4 + r;
                    if (row < M) Cb[(size_t)row * cbld + colg] = f2bf(acc[mi][ni][r]);
                }
            }
        }
    } else {
        #pragma unroll
        for (int mi = 0; mi < 4; ++mi) {
            #pragma unroll
            for (int ni = 0; ni < 4; ++ni) {
                if (!val[ni]) continue;
                const int colg = bn + wn * 64 + ni * 16 + fr;
                #pragma unroll
                for (int r = 0; r < 4; ++r) {
                    const int row = bm + wm * 64 + mi * 16 + g * 4 + r;
                    if (row < M) Cf[(size_t)row * ldc + colg] = acc[mi][ni][r];
                }
            }
        }
    }
}

// ---------------------------------------------------------------------------
// combine partials (transposed pm/ps) -> rowadd = log(pgen) - m - log(s)
// ---------------------------------------------------------------------------
__global__ __launch_bounds__(256) void combine_kernel(
    const float* __restrict__ pm, const float* __restrict__ ps,
    const float* __restrict__ pgen, float* __restrict__ rowadd)
{
    const int row = blockIdx.x;
    const int tid = threadIdx.x;
    float m = -1e30f, s = 0.f;
    for (int i = tid; i < cPAN; i += 256) {
        const float mi = pm[(size_t)i * cMQ + row];
        const float si = ps[(size_t)i * cMQ + row];
        const float nm = fmaxf(m, mi);
        s = s * __expf(m - nm) + si * __expf(mi - nm);
        m = nm;
    }
    #pragma unroll
    for (int sw = 1; sw < 64; sw <<= 1) {
        const float mo = __shfl_xor(m, sw);
        const float so = __shfl_xor(s, sw);
        const float nm = fmaxf(m, mo);
        s = s * __expf(m - nm) + so * __expf(mo - nm);
        m = nm;
    }
    __shared__ float rm[4], rs[4];
    if ((tid & 63) == 0) { rm[tid >> 6] = m; rs[tid >> 6] = s; }
    __syncthreads();
    if (tid == 0) {
        m = rm[0]; s = rs[0];
        #pragma unroll
        for (int i = 1; i < 4; ++i) {
            const float nm = fmaxf(m, rm[i]);
            s = s * __expf(m - nm) + rs[i] * __expf(rm[i] - nm);
            m = nm;
        }
        rowadd[row] = __logf(pgen[row]) - m - __logf(s);
    }
}

// ---------------------------------------------------------------------------
// Flat disjoint transform (big-ws path): read bf16 logits from lb (stride cV),
// write fp32 log-probs to out. Fully parallel, no ordering constraints.
// Grid (13, 1024): thread i handles elems [8i, 8i+8); i==6250 writes the
// 50-elem LOGMIN tail.
// ---------------------------------------------------------------------------
__global__ __launch_bounds__(512) void transform_flat(
    float* __restrict__ out, const ushort* __restrict__ lb,
    const float* __restrict__ rowadd)
{
    const int row = blockIdx.y;
    const float a = rowadd[row];
    constexpr float LOGMIN = -20.72326583694641f;   // log(1e-9)
    const ushort* src = lb + (size_t)row * cV;
    float* dst = out + (size_t)row * cVEXT;
    constexpr int NI = cV / 8;   // 6250
    for (int i = blockIdx.x * 512 + threadIdx.x; i <= NI; i += gridDim.x * 512) {
        if (i < NI) {
            const short8v sv = *(const short8v*)(src + (size_t)i * 8);
            const int v = i * 8;
            #pragma unroll
            for (int j = 0; j < 4; ++j) {
                float2 o;
                o.x = fmaxf(bf2f((ushort)sv[2 * j])     + a, LOGMIN);
                o.y = fmaxf(bf2f((ushort)sv[2 * j + 1]) + a, LOGMIN);
                *(float2*)&dst[v + 2 * j] = o;
            }
        } else {
            #pragma unroll
            for (int v = cV; v < cVEXT; v += 2) {
                float2 o; o.x = LOGMIN; o.y = LOGMIN;
                *(float2*)&dst[v] = o;
            }
        }
    }
}

// ---------------------------------------------------------------------------
// scatter fixup (big-ws path): out[row,p] = log(max(exp(out[row,p])+sum, 1e-9))
// ---------------------------------------------------------------------------
__global__ __launch_bounds__(256) void fixup_kernel(
    float* __restrict__ out, const int* __restrict__ ebev,
    const float* __restrict__ attn)
{
    const int row = blockIdx.x;
    const int b = row / cT;
    const int tid = threadIdx.x;
    __shared__ int   pos[cS];
    __shared__ float add[cS];
    for (int s = tid; s < cS; s += 256) {
        pos[s] = ebev[b * cS + s];
        add[s] = attn[(size_t)row * cS + s];
    }
    __syncthreads();
    float* rowf = out + (size_t)row * cVEXT;
    for (int s = tid; s < cS; s += 256) {
        const int p = pos[s];
        bool leader = true;
        for (int s2 = 0; s2 < s; ++s2)
            if (pos[s2] == p) { leader = false; break; }
        if (!leader) continue;
        float sum = add[s];
        for (int s2 = s + 1; s2 < cS; ++s2)
            if (pos[s2] == p) sum += add[s2];
        const float base = __expf(rowf[p]);
        rowf[p] = __logf(fmaxf(base + sum, 1e-9f));
    }
}

// ---------------------------------------------------------------------------
// Fallback (small ws): segmented in-place expand + fixup (r6 proven)
// ---------------------------------------------------------------------------
__global__ __launch_bounds__(512) void transform_inplace(
    float* __restrict__ out, const float* __restrict__ rowadd,
    const int* __restrict__ ebev, const float* __restrict__ attn)
{
    const int row = blockIdx.x;
    const int b   = row / cT;
    const int tid = threadIdx.x;
    constexpr float LOGMIN = -20.72326583694641f;

    __shared__ int   pos[cS];
    __shared__ float add[cS];
    for (int s = tid; s < cS; s += 512) {
        pos[s] = ebev[b * cS + s];
        add[s] = attn[(size_t)row * cS + s];
    }

    const float a = rowadd[row];
    ushort* rowu = (ushort*)out + (size_t)row * cCBLD;
    float*  rowf = out + (size_t)row * cVEXT;

    #pragma unroll 1
    for (int L = 32768; L >= 2; L >>= 1) {
        const int hi = (2 * L < cVEXT) ? 2 * L : cVEXT;
        for (int i = L + 2 * tid; i < hi; i += 1024) {
            const float x0 = bf2f(rowu[i]);
            const float x1 = bf2f(rowu[i + 1]);
            float2 o;
            o.x = (i     < cV) ? fmaxf(x0 + a, LOGMIN) : LOGMIN;
            o.y = (i + 1 < cV) ? fmaxf(x1 + a, LOGMIN) : LOGMIN;
            *(float2*)&rowf[i] = o;
        }
        __syncthreads();
    }
    if (tid == 0) {
        const float x1 = bf2f(rowu[1]);
        const float x0 = bf2f(rowu[0]);
        rowf[1] = fmaxf(x1 + a, LOGMIN);
        rowf[0] = fmaxf(x0 + a, LOGMIN);
    }
    __syncthreads();

    for (int s = tid; s < cS; s += 512) {
        const int p = pos[s];
        bool leader = true;
        for (int s2 = 0; s2 < s; ++s2)
            if (pos[s2] == p) { leader = false; break; }
        if (!leader) continue;
        float sum = add[s];
        for (int s2 = s + 1; s2 < cS; ++s2)
            if (pos[s2] == p) sum += add[s2];
        const float base = __expf(rowf[p]);
        rowf[p] = __logf(fmaxf(base + sum, 1e-9f));
    }
}

// ---------------------------------------------------------------------------
// p_gen = sigmoid(x . pgen_w + pgen_b)
// ---------------------------------------------------------------------------
__global__ __launch_bounds__(64) void pgen_kernel(
    const float* __restrict__ x, const float* __restrict__ w,
    const float* __restrict__ b, float* __restrict__ pgen)
{
    const int row = blockIdx.x;
    const int lane = threadIdx.x;
    const float* xr = x + (size_t)row * cD;
    float s = 0.f;
    for (int i = lane; i < cD; i += 64) s += xr[i] * w[i];
    #pragma unroll
    for (int off = 32; off; off >>= 1) s += __shfl_down(s, off);
    if (lane == 0) pgen[row] = 1.f / (1.f + __expf(-(s + b[0])));
}

// ---------------------------------------------------------------------------
// attention distribution (scaled by 1-pgen)
// ---------------------------------------------------------------------------
__global__ __launch_bounds__(256) void attn_kernel(
    const float* __restrict__ q, const float* __restrict__ k,
    const int* __restrict__ src_mask, const float* __restrict__ pgen,
    float* __restrict__ attn)
{
    constexpr float scale = 0.04419417382415922f;  // 1/sqrt(512)
    const int row = blockIdx.x;      // b*T + t
    const int b = row / cT;
    const int tid = threadIdx.x;

    __shared__ __align__(16) float qs[cD];
    __shared__ float sc[cS];
    __shared__ float red[4];

    for (int i = tid; i < cD; i += 256) qs[i] = q[(size_t)row * cD + i];
    __syncthreads();

    for (int s = tid; s < cS; s += 256) {
        const float* kr = k + ((size_t)b * cS + s) * cD;
        float dot = 0.f;
        #pragma unroll 4
        for (int i = 0; i < cD; i += 4) {
            float4 kv = *(const float4*)(kr + i);
            float4 qv = *(const float4*)(qs + i);
            dot += qv.x * kv.x + qv.y * kv.y + qv.z * kv.z + qv.w * kv.w;
        }
        float v = dot * scale;
        if (src_mask[b * cS + s] == 0) v = -1e9f;
        sc[s] = v;
    }
    __syncthreads();

    float m = -3.4e38f;
    for (int s = tid; s < cS; s += 256) m = fmaxf(m, sc[s]);
    #pragma unroll
    for (int off = 32; off; off >>= 1) m = fmaxf(m, __shfl_down(m, off));
    if ((tid & 63) == 0) red[tid >> 6] = m;
    __syncthreads();
    m = fmaxf(fmaxf(red[0], red[1]), fmaxf(red[2], red[3]));
    __syncthreads();

    float sum = 0.f;
    for (int s = tid; s < cS; s += 256) {
        float e = __expf(sc[s] - m);
        sc[s] = e;
        sum += e;
    }
    #pragma unroll
    for (int off = 32; off; off >>= 1) sum += __shfl_down(sum, off);
    if ((tid & 63) == 0) red[tid >> 6] = sum;
    __syncthreads();
    sum = red[0] + red[1] + red[2] + red[3];

    const float w = (1.f - pgen[row]) / sum;
    for (int s = tid; s < cS; s += 256)
        attn[(size_t)row * cS + s] = sc[s] * w;
}

extern "C" void kernel_launch(void* const* d_in, const int* in_sizes, int n_in,
                              void* d_out, int out_size, void* d_ws, size_t ws_size,
                              hipStream_t stream)
{
    const float* x      = (const float*)d_in[0];   // (B,T,D)
    const float* enc    = (const float*)d_in[1];   // (B,S,D)
    const int*   mask   = (const int*)d_in[2];     // (B,1,S)
    const int*   ebev   = (const int*)d_in[3];     // (B,S)
    const float* fc_w   = (const float*)d_in[5];   // (V,D)
    const float* fc_b   = (const float*)d_in[6];   // (V,)
    const float* pgen_w = (const float*)d_in[7];   // (1,D)
    const float* pgen_b = (const float*)d_in[8];   // (1,)
    const float* wq     = (const float*)d_in[9];   // (D,D)
    const float* bq     = (const float*)d_in[10];  // (D,)
    const float* wk     = (const float*)d_in[11];  // (D,D)
    const float* bk     = (const float*)d_in[12];  // (D,)
    float* out = (float*)d_out;

    // workspace layout
    float* ws     = (float*)d_ws;
    float* q      = ws;                                   // 1024*512
    float* kbuf   = q + (size_t)cB * cT * cD;             // 1600*512
    float* pgen   = kbuf + (size_t)cB * cS * cD;          // 1024
    float* attn   = pgen + cB * cT;                       // 1024*400
    float* pm     = attn + (size_t)cB * cT * cS;          // 391*1024 (transposed)
    float* ps     = pm + (size_t)cPAN * cMQ;              // 391*1024
    float* rowadd = ps + (size_t)cPAN * cMQ;              // 1024
    ushort* xb    = (ushort*)(rowadd + cMQ);
    ushort* encb  = xb + (size_t)cB * cT * cD;
    ushort* wqb   = encb + (size_t)cB * cS * cD;
    ushort* wkb   = wqb + (size_t)cD * cD;
    ushort* tail  = wkb + (size_t)cD * cD;   // big: logits buf; small: wb

    const size_t base_bytes = (size_t)((char*)tail - (char*)d_ws);
    const bool big = ws_size >= base_bytes + (size_t)cMQ * cV * 2 + 1024;

    const dim3 blk(256);
    const int MQ = cMQ;        // 1024
    const int MK = cB * cS;    // 1600

    ushort* wb;        // bf16 W
    ushort* logitsb;   // bf16 logits (big path)
    int     cbld;
    if (big) {
        wb = (ushort*)d_out;   // W lives in d_out until transform consumes it
        logitsb = tail;
        cbld = cV;
    } else {
        wb = tail;
        logitsb = (ushort*)d_out;  // in-slot
        cbld = cCBLD;
    }

    // casts
    cast_kernel<<<dim3(512), blk, 0, stream>>>(x, xb, (cB * cT * cD) / 4);
    cast_kernel<<<dim3(512), blk, 0, stream>>>(enc, encb, (cB * cS * cD) / 4);
    cast_kernel<<<dim3(256), blk, 0, stream>>>(wq, wqb, (cD * cD) / 4);
    cast_kernel<<<dim3(256), blk, 0, stream>>>(wk, wkb, (cD * cD) / 4);
    cast_kernel<<<dim3(2048), blk, 0, stream>>>(fc_w, wb, (cV * cD) / 4);

    // projections (bf16 MFMA, fp32 out)
    gemm2<false><<<dim3(MQ / 128, cD / 128), blk, 0, stream>>>(
        xb, wqb, bq, q, nullptr, 0, nullptr, nullptr, MQ, cD, cD, cD);
    gemm2<false><<<dim3((MK + 127) / 128, cD / 128), blk, 0, stream>>>(
        encb, wkb, bk, kbuf, nullptr, 0, nullptr, nullptr, MK, cD, cD, cD);
    pgen_kernel<<<dim3(MQ), dim3(64), 0, stream>>>(x, pgen_w, pgen_b, pgen);

    // attention distribution
    attn_kernel<<<dim3(MQ), blk, 0, stream>>>(q, kbuf, mask, pgen, attn);

    // big logits GEMM: bf16 C + softmax partials (transposed)
    gemm2<true><<<dim3(MQ / 128, cPAN), blk, 0, stream>>>(
        xb, wb, fc_b, nullptr, logitsb, cbld, pm, ps, MQ, cV, cD, 0);

    // combine partials -> rowadd
    combine_kernel<<<dim3(MQ), blk, 0, stream>>>(pm, ps, pgen, rowadd);

    if (big) {
        transform_flat<<<dim3(13, MQ), dim3(512), 0, stream>>>(out, logitsb, rowadd);
        fixup_kernel<<<dim3(MQ), blk, 0, stream>>>(out, ebev, attn);
    } else {
        transform_inplace<<<dim3(MQ), dim3(512), 0, stream>>>(out, rowadd, ebev, attn);
    }
}